// Round 10
// baseline (251.990 us; speedup 1.0000x reference)
//
#include <hip/hip_runtime.h>
#include <math.h>

#define N_NODES 50000
#define IN_DIM 8
#define HID 32
#define D1 128   // HID * HEADS

// hierarchical scan config: 256 thr × 4 elems = 1024 per block
#define SB 1024
#define NB ((N_NODES + SB - 1) / SB)   // 49

// XCD-partitioned CSR build: 8 groups (g = blockIdx&7 -> same XCD under
// round-robin dispatch), each group owns dst range of N_NODES/8 = 6250.
#define FG 8
#define FB 128          // blocks per group
#define GRANGE (N_NODES / FG)

// ---------------------------------------------------------------------------
// CSR build: histogram -> 2-stage scan -> fill (src ids sorted by dst)
// ---------------------------------------------------------------------------
__global__ void k_hist(const int* __restrict__ dst, int* __restrict__ cnt,
                       int n_edges) {
    const int g = blockIdx.x & (FG - 1);
    const int blk = blockIdx.x >> 3;
    const int lo = g * GRANGE, hi = lo + GRANGE;
    const int base = blk * blockDim.x + threadIdx.x;
    const int step = FB * blockDim.x;
    for (int i = base; i * 4 < n_edges; i += step) {
        const int4 d4 = *(const int4*)&dst[i * 4];
        if (d4.x >= lo && d4.x < hi) atomicAdd(&cnt[d4.x], 1);
        if (d4.y >= lo && d4.y < hi) atomicAdd(&cnt[d4.y], 1);
        if (d4.z >= lo && d4.z < hi) atomicAdd(&cnt[d4.z], 1);
        if (d4.w >= lo && d4.w < hi) atomicAdd(&cnt[d4.w], 1);
    }
}

// stage A: per-block sums (49 blocks)
__global__ void k_scan_a(const int* __restrict__ cnt, int* __restrict__ bsum) {
    const int t = threadIdx.x;
    const int base = blockIdx.x * SB + t * 4;
    int4 v = {0, 0, 0, 0};
    if (base + 3 < N_NODES) v = *(const int4*)&cnt[base];
    int s = v.x + v.y + v.z + v.w;
#pragma unroll
    for (int off = 32; off > 0; off >>= 1) s += __shfl_xor(s, off);
    __shared__ int w[4];
    if ((t & 63) == 0) w[t >> 6] = s;
    __syncthreads();
    if (t == 0) bsum[blockIdx.x] = w[0] + w[1] + w[2] + w[3];
}

// stage C (merged with old stage B): each block redundantly wave-scans the
// NB block sums (NB=49 <= 64 lanes) for its own global offset, then does the
// per-block exclusive scan of cnt -> offs[]; also initializes cursor = offs
// so k_fill can atomicAdd(cursor) directly.  Last block writes offs[N_NODES].
__global__ void k_scan_c(const int* __restrict__ cnt, const int* __restrict__ bsum,
                         int* __restrict__ offs, int* __restrict__ cursor) {
    const int t = threadIdx.x;
    const int lane = t & 63, wid = t >> 6;
    __shared__ int s_boff;
    __shared__ int wtot[4];
    if (t < 64) {                                   // wave 0: scan bsum
        int v = (t < NB) ? bsum[t] : 0;
        int incl = v;
#pragma unroll
        for (int off = 1; off < 64; off <<= 1) {
            int u = __shfl_up(incl, off);
            if (t >= off) incl += u;
        }
        if (t == blockIdx.x) s_boff = incl - v;     // exclusive prefix @ this block
        if (blockIdx.x == NB - 1 && t == NB - 1) offs[N_NODES] = incl;  // total
    }
    const int base = blockIdx.x * SB + t * 4;
    int4 v = {0, 0, 0, 0};
    if (base + 3 < N_NODES) v = *(const int4*)&cnt[base];
    const int tsum = v.x + v.y + v.z + v.w;
    int incl = tsum;
#pragma unroll
    for (int off = 1; off < 64; off <<= 1) {
        int u = __shfl_up(incl, off);
        if (lane >= off) incl += u;
    }
    if (lane == 63) wtot[wid] = incl;
    __syncthreads();
    int woff = 0;
    for (int w = 0; w < wid; ++w) woff += wtot[w];
    const int excl = s_boff + woff + incl - tsum;
    if (base + 3 < N_NODES) {
        int4 o;
        o.x = excl;
        o.y = excl + v.x;
        o.z = excl + v.x + v.y;
        o.w = excl + v.x + v.y + v.z;
        *(int4*)&offs[base] = o;
        *(int4*)&cursor[base] = o;
    }
}

__global__ void k_fill(const int* __restrict__ src, const int* __restrict__ dst,
                       int* __restrict__ cursor,
                       int* __restrict__ esrc, int n_edges) {
    const int g = blockIdx.x & (FG - 1);
    const int blk = blockIdx.x >> 3;
    const int lo = g * GRANGE, hi = lo + GRANGE;
    const int base = blk * blockDim.x + threadIdx.x;
    const int step = FB * blockDim.x;
    for (int i = base; i * 4 < n_edges; i += step) {
        const int4 d4 = *(const int4*)&dst[i * 4];
        const int4 s4 = *(const int4*)&src[i * 4];
        if (d4.x >= lo && d4.x < hi) esrc[atomicAdd(&cursor[d4.x], 1)] = s4.x;
        if (d4.y >= lo && d4.y < hi) esrc[atomicAdd(&cursor[d4.y], 1)] = s4.y;
        if (d4.z >= lo && d4.z < hi) esrc[atomicAdd(&cursor[d4.z], 1)] = s4.z;
        if (d4.w >= lo && d4.w < hi) esrc[atomicAdd(&cursor[d4.w], 1)] = s4.w;
    }
}

// ---------------------------------------------------------------------------
// s1/d1 via folded attention vectors:  s1[n] = x[n]·(W1 a_src), etc.
// ---------------------------------------------------------------------------
__global__ void k_sd1(const float* __restrict__ x, const float* __restrict__ W1,
                      const float* __restrict__ a1,
                      float* __restrict__ s1, float* __restrict__ d1) {
    __shared__ float bs[IN_DIM], bd[IN_DIM];
    const int t = threadIdx.x;
    if (t < 16) {
        const int k = t & 7;
        const float* av = a1 + ((t < 8) ? 0 : D1);
        float acc = 0.f;
        for (int j = 0; j < D1; ++j) acc += W1[k * D1 + j] * av[j];
        if (t < 8) bs[k] = acc; else bd[k] = acc;
    }
    __syncthreads();
    const int node = blockIdx.x * blockDim.x + t;
    if (node >= N_NODES) return;
    const float4 x0 = *(const float4*)&x[node * 8];
    const float4 x1 = *(const float4*)&x[node * 8 + 4];
    s1[node] = x0.x*bs[0] + x0.y*bs[1] + x0.z*bs[2] + x0.w*bs[3]
             + x1.x*bs[4] + x1.y*bs[5] + x1.z*bs[6] + x1.w*bs[7];
    d1[node] = x0.x*bd[0] + x0.y*bd[1] + x0.z*bd[2] + x0.w*bd[3]
             + x1.x*bd[4] + x1.y*bd[5] + x1.z*bd[6] + x1.w*bd[7];
}

// ---------------------------------------------------------------------------
// Layer-1 aggregation in INPUT space (8-dim):  xa[n] = sum_e w_e * x[src_e].
// One wave/node.  Fast path deg<=64: single register-resident edge chunk.
// 4 lanes per edge (float2 each) -> 16 edges in flight per iteration.
// ---------------------------------------------------------------------------
__global__ void k_aggr_x(const int* __restrict__ esrc, const int* __restrict__ offs,
                         const float* __restrict__ s, const float* __restrict__ d,
                         const float* __restrict__ x, float* __restrict__ xa) {
    const int node = (blockIdx.x * blockDim.x + threadIdx.x) >> 6;
    const int lane = threadIdx.x & 63;
    if (node >= N_NODES) return;
    const int start = offs[node], end = offs[node + 1];
    const int deg = end - start;
    const float dn = d[node];
    const int slot = lane >> 2;      // 16 edge slots
    const int cp = lane & 3;         // float2 -> cols 2cp, 2cp+1
    float2 acc = {0.f, 0.f};
    float inv;
    if (deg <= 64) {
        int sev = 0; float wv = 0.f;
        if (lane < deg) {
            sev = esrc[start + lane];
            float a = s[sev] + dn;
            a = a > 0.f ? a : 0.2f * a;
            wv = expf(a);
        }
        float sum = wv;
#pragma unroll
        for (int off = 32; off > 0; off >>= 1) sum += __shfl_xor(sum, off);
        inv = 1.f / (sum + 1e-9f);
        for (int i = 0; i < deg; i += 16) {
            const int idx = i + slot;
            const float w = __shfl(wv, idx);
            const int se = __shfl(sev, idx);
            if (idx < deg) {
                const float2 v = *(const float2*)&x[se * IN_DIM + cp * 2];
                acc.x += w * v.x;
                acc.y += w * v.y;
            }
        }
    } else {
        float sum = 0.f;
        for (int e = start + lane; e < end; e += 64) {
            float a = s[esrc[e]] + dn;
            a = a > 0.f ? a : 0.2f * a;
            sum += expf(a);
        }
#pragma unroll
        for (int off = 32; off > 0; off >>= 1) sum += __shfl_xor(sum, off);
        inv = 1.f / (sum + 1e-9f);
        for (int chunk = start; chunk < end; chunk += 64) {
            const int cnt = min(64, end - chunk);
            int sev = 0; float wv = 0.f;
            if (lane < cnt) {
                sev = esrc[chunk + lane];
                float a = s[sev] + dn;
                a = a > 0.f ? a : 0.2f * a;
                wv = expf(a);
            }
            for (int i = 0; i < cnt; i += 16) {
                const int idx = i + slot;
                const float w = __shfl(wv, idx);
                const int se = __shfl(sev, idx);
                if (idx < cnt) {
                    const float2 v = *(const float2*)&x[se * IN_DIM + cp * 2];
                    acc.x += w * v.x;
                    acc.y += w * v.y;
                }
            }
        }
    }
    acc.x *= inv;  acc.y *= inv;
#pragma unroll
    for (int off = 4; off < 64; off <<= 1) {       // reduce over slot bits 2..5
        acc.x += __shfl_xor(acc.x, off);
        acc.y += __shfl_xor(acc.y, off);
    }
    if (lane < 4) *(float2*)&xa[node * IN_DIM + lane * 2] = acc;
}

// ---------------------------------------------------------------------------
// Fused node mid, 4 THREADS PER NODE (column split).  Thread q of a node
// owns output cols [8q, 8q+8).  h_k recomputed per thread (8 FMA, s_load
// weights, wave-uniform k -> whole wave touches one W2 row per iter).
// ---------------------------------------------------------------------------
__global__ void k_node_mid(const float* __restrict__ xa,
                           const float* __restrict__ W1,
                           const float* __restrict__ W2,
                           const float* __restrict__ a2,
                           float* __restrict__ Wh2,
                           float* __restrict__ s2, float* __restrict__ d2) {
    const int tid = blockIdx.x * blockDim.x + threadIdx.x;
    const int node = tid >> 2;
    const int q = tid & 3;                 // column quarter
    if (node >= N_NODES) return;
    const float4 x0 = *(const float4*)&xa[node * 8];
    const float4 x1 = *(const float4*)&xa[node * 8 + 4];
    float acc[8];
#pragma unroll
    for (int j = 0; j < 8; ++j) acc[j] = 0.f;
    const float* W2q = W2 + q * 8;
#pragma unroll 4
    for (int k = 0; k < D1; ++k) {
        float h = x0.x * W1[0 * D1 + k] + x0.y * W1[1 * D1 + k]
                + x0.z * W1[2 * D1 + k] + x0.w * W1[3 * D1 + k]
                + x1.x * W1[4 * D1 + k] + x1.y * W1[5 * D1 + k]
                + x1.z * W1[6 * D1 + k] + x1.w * W1[7 * D1 + k];
        h = h > 0.f ? h : (expf(h) - 1.f);       // elu
        const float4 w0 = *(const float4*)&W2q[k * HID];
        const float4 w1 = *(const float4*)&W2q[k * HID + 4];
        acc[0] += h * w0.x;  acc[1] += h * w0.y;
        acc[2] += h * w0.z;  acc[3] += h * w0.w;
        acc[4] += h * w1.x;  acc[5] += h * w1.y;
        acc[6] += h * w1.z;  acc[7] += h * w1.w;
    }
    float ss = 0.f, dd = 0.f;
#pragma unroll
    for (int j = 0; j < 8; ++j) {
        ss += acc[j] * a2[q * 8 + j];
        dd += acc[j] * a2[HID + q * 8 + j];
    }
    ss += __shfl_xor(ss, 1);  ss += __shfl_xor(ss, 2);
    dd += __shfl_xor(dd, 1);  dd += __shfl_xor(dd, 2);
    if (q == 0) { s2[node] = ss; d2[node] = dd; }
    float4* o = (float4*)&Wh2[node * HID + q * 8];
    o[0] = make_float4(acc[0], acc[1], acc[2], acc[3]);
    o[1] = make_float4(acc[4], acc[5], acc[6], acc[7]);
}

// ---------------------------------------------------------------------------
// Layer-2 aggregation + FUSED MLP HEAD.  One wave/node.  Fast path deg<=64.
// 16 lanes per edge (float2 each) -> 4 edges in flight per iteration.
// ---------------------------------------------------------------------------
__global__ void k_aggr32_head(const int* __restrict__ esrc, const int* __restrict__ offs,
                              const float* __restrict__ s, const float* __restrict__ d,
                              const float* __restrict__ Wh,
                              const float* __restrict__ hw1, const float* __restrict__ hb1,
                              const float* __restrict__ hw2, const float* __restrict__ hb2,
                              float* __restrict__ scores) {
    const int node = (blockIdx.x * blockDim.x + threadIdx.x) >> 6;
    const int lane = threadIdx.x & 63;
    if (node >= N_NODES) return;
    const int start = offs[node], end = offs[node + 1];
    const int deg = end - start;
    const float dn = d[node];
    const int slot = lane >> 4;      // 4 edge slots
    const int cp = lane & 15;        // float2 -> cols 2cp, 2cp+1
    float2 acc = {0.f, 0.f};
    float inv;
    if (deg <= 64) {
        int sev = 0; float wv = 0.f;
        if (lane < deg) {
            sev = esrc[start + lane];
            float a = s[sev] + dn;
            a = a > 0.f ? a : 0.2f * a;
            wv = expf(a);
        }
        float sum = wv;
#pragma unroll
        for (int off = 32; off > 0; off >>= 1) sum += __shfl_xor(sum, off);
        inv = 1.f / (sum + 1e-9f);
        for (int i = 0; i < deg; i += 4) {
            const int idx = i + slot;
            const float w = __shfl(wv, idx);
            const int se = __shfl(sev, idx);
            if (idx < deg) {
                const float2 v = *(const float2*)&Wh[se * HID + cp * 2];
                acc.x += w * v.x;
                acc.y += w * v.y;
            }
        }
    } else {
        float sum = 0.f;
        for (int e = start + lane; e < end; e += 64) {
            float a = s[esrc[e]] + dn;
            a = a > 0.f ? a : 0.2f * a;
            sum += expf(a);
        }
#pragma unroll
        for (int off = 32; off > 0; off >>= 1) sum += __shfl_xor(sum, off);
        inv = 1.f / (sum + 1e-9f);
        for (int chunk = start; chunk < end; chunk += 64) {
            const int cnt = min(64, end - chunk);
            int sev = 0; float wv = 0.f;
            if (lane < cnt) {
                sev = esrc[chunk + lane];
                float a = s[sev] + dn;
                a = a > 0.f ? a : 0.2f * a;
                wv = expf(a);
            }
            for (int i = 0; i < cnt; i += 4) {
                const int idx = i + slot;
                const float w = __shfl(wv, idx);
                const int se = __shfl(sev, idx);
                if (idx < cnt) {
                    const float2 v = *(const float2*)&Wh[se * HID + cp * 2];
                    acc.x += w * v.x;
                    acc.y += w * v.y;
                }
            }
        }
    }
    acc.x *= inv;  acc.y *= inv;
#pragma unroll
    for (int off = 16; off < 64; off <<= 1) {      // reduce over slot bits 4..5
        acc.x += __shfl_xor(acc.x, off);
        acc.y += __shfl_xor(acc.y, off);
    }
    // ---- fused head ----
    const int c = lane & 31;
    const float hx = __shfl(acc.x, c >> 1);
    const float hy = __shfl(acc.y, c >> 1);
    float v = (c & 1) ? hy : hx;
    const float h = v > 0.f ? v : (expf(v) - 1.f);   // elu
    float z = hb1[c];
#pragma unroll
    for (int k = 0; k < HID; ++k) {
        const float hk = __shfl(h, k);   // h_k lives in lane k
        z += hk * hw1[k * HID + c];
    }
    z = 0.5f * z * (1.f + erff(z * 0.7071067811865475f));  // exact gelu
    float sc = z * hw2[c];
#pragma unroll
    for (int off = 16; off > 0; off >>= 1) sc += __shfl_xor(sc, off);
    if (lane == 0) scores[node] = sc + hb2[0];
}

// ---------------------------------------------------------------------------
extern "C" void kernel_launch(void* const* d_in, const int* in_sizes, int n_in,
                              void* d_out, int out_size, void* d_ws, size_t ws_size,
                              hipStream_t stream) {
    const float* x   = (const float*)d_in[0];
    const int*   ei  = (const int*)d_in[1];
    const float* W1  = (const float*)d_in[2];
    const float* a1  = (const float*)d_in[3];
    const float* W2  = (const float*)d_in[4];
    const float* a2  = (const float*)d_in[5];
    const float* hw1 = (const float*)d_in[6];
    const float* hb1 = (const float*)d_in[7];
    const float* hw2 = (const float*)d_in[8];
    const float* hb2 = (const float*)d_in[9];
    float* out = (float*)d_out;

    const int n_edges = in_sizes[1] / 2;
    const int* src = ei;
    const int* dst = ei + n_edges;

    // workspace carve-up
    float* p = (float*)d_ws;
    float* xa   = p; p += (size_t)N_NODES * IN_DIM;
    float* Wh2  = p; p += (size_t)N_NODES * HID;
    float* s1   = p; p += N_NODES;
    float* d1   = p; p += N_NODES;
    float* s2   = p; p += N_NODES;
    float* d2   = p; p += N_NODES;
    int* cnt    = (int*)p; p += N_NODES;        // histogram counts
    int* cursor = (int*)p; p += N_NODES;        // fill cursors (init by scan_c)
    int* offs   = (int*)p; p += N_NODES + 1;    // CSR offsets
    int* esrc   = (int*)p; p += n_edges;        // src ids sorted by dst
    int* bsum   = (int*)p; p += NB;             // scan block sums

    hipMemsetAsync(cnt, 0, N_NODES * sizeof(int), stream);

    const int WAVE_BLOCKS = (N_NODES * 64 + 255) / 256;

    // CSR build (XCD-partitioned atomics/scatter)
    k_hist<<<FG * FB, 256, 0, stream>>>(dst, cnt, n_edges);
    k_scan_a<<<NB, 256, 0, stream>>>(cnt, bsum);
    k_scan_c<<<NB, 256, 0, stream>>>(cnt, bsum, offs, cursor);
    k_fill<<<FG * FB, 256, 0, stream>>>(src, dst, cursor, esrc, n_edges);

    // ----- layer 1 (aggregated in 8-dim input space; Wh1 never built) -----
    k_sd1<<<(N_NODES + 255) / 256, 256, 0, stream>>>(x, W1, a1, s1, d1);
    k_aggr_x<<<WAVE_BLOCKS, 256, 0, stream>>>(esrc, offs, s1, d1, x, xa);

    // ----- layer 2 (4-thread-per-node mid; aggregation fused with head) -----
    k_node_mid<<<(N_NODES * 4 + 255) / 256, 256, 0, stream>>>(xa, W1, W2, a2, Wh2, s2, d2);
    k_aggr32_head<<<WAVE_BLOCKS, 256, 0, stream>>>(esrc, offs, s2, d2, Wh2,
                                                   hw1, hb1, hw2, hb2, out);
}

// Round 11
// 239.184 us; speedup vs baseline: 1.0535x; 1.0535x over previous
//
#include <hip/hip_runtime.h>
#include <math.h>

#define N_NODES 50000
#define IN_DIM 8
#define HID 32
#define D1 128   // HID * HEADS

// hierarchical scan config: 256 thr × 4 elems = 1024 per block
#define SB 1024
#define NB ((N_NODES + SB - 1) / SB)   // 49

// XCD-partitioned CSR build: 8 groups (g = blockIdx&7 -> same XCD under
// round-robin dispatch), each group owns dst range of N_NODES/8 = 6250.
#define FG 8
#define FB 128          // blocks per group
#define GRANGE (N_NODES / FG)

// ---------------------------------------------------------------------------
// CSR build: histogram -> 2-stage scan -> fill (src ids sorted by dst)
// ---------------------------------------------------------------------------
__global__ void k_hist(const int* __restrict__ dst, int* __restrict__ cnt,
                       int n_edges) {
    const int g = blockIdx.x & (FG - 1);
    const int blk = blockIdx.x >> 3;
    const int lo = g * GRANGE, hi = lo + GRANGE;
    const int base = blk * blockDim.x + threadIdx.x;
    const int step = FB * blockDim.x;
    for (int i = base; i * 4 < n_edges; i += step) {
        const int4 d4 = *(const int4*)&dst[i * 4];
        if (d4.x >= lo && d4.x < hi) atomicAdd(&cnt[d4.x], 1);
        if (d4.y >= lo && d4.y < hi) atomicAdd(&cnt[d4.y], 1);
        if (d4.z >= lo && d4.z < hi) atomicAdd(&cnt[d4.z], 1);
        if (d4.w >= lo && d4.w < hi) atomicAdd(&cnt[d4.w], 1);
    }
}

// stage A: per-block sums (49 blocks)
__global__ void k_scan_a(const int* __restrict__ cnt, int* __restrict__ bsum) {
    const int t = threadIdx.x;
    const int base = blockIdx.x * SB + t * 4;
    int4 v = {0, 0, 0, 0};
    if (base + 3 < N_NODES) v = *(const int4*)&cnt[base];
    int s = v.x + v.y + v.z + v.w;
#pragma unroll
    for (int off = 32; off > 0; off >>= 1) s += __shfl_xor(s, off);
    __shared__ int w[4];
    if ((t & 63) == 0) w[t >> 6] = s;
    __syncthreads();
    if (t == 0) bsum[blockIdx.x] = w[0] + w[1] + w[2] + w[3];
}

// stage C: each block redundantly wave-scans the NB block sums (NB=49 <= 64
// lanes) for its own global offset, then per-block exclusive scan of cnt ->
// offs[]; also initializes cursor = offs.  Last block writes offs[N_NODES].
__global__ void k_scan_c(const int* __restrict__ cnt, const int* __restrict__ bsum,
                         int* __restrict__ offs, int* __restrict__ cursor) {
    const int t = threadIdx.x;
    const int lane = t & 63, wid = t >> 6;
    __shared__ int s_boff;
    __shared__ int wtot[4];
    if (t < 64) {                                   // wave 0: scan bsum
        int v = (t < NB) ? bsum[t] : 0;
        int incl = v;
#pragma unroll
        for (int off = 1; off < 64; off <<= 1) {
            int u = __shfl_up(incl, off);
            if (t >= off) incl += u;
        }
        if (t == blockIdx.x) s_boff = incl - v;     // exclusive prefix @ this block
        if (blockIdx.x == NB - 1 && t == NB - 1) offs[N_NODES] = incl;  // total
    }
    const int base = blockIdx.x * SB + t * 4;
    int4 v = {0, 0, 0, 0};
    if (base + 3 < N_NODES) v = *(const int4*)&cnt[base];
    const int tsum = v.x + v.y + v.z + v.w;
    int incl = tsum;
#pragma unroll
    for (int off = 1; off < 64; off <<= 1) {
        int u = __shfl_up(incl, off);
        if (lane >= off) incl += u;
    }
    if (lane == 63) wtot[wid] = incl;
    __syncthreads();
    int woff = 0;
    for (int w = 0; w < wid; ++w) woff += wtot[w];
    const int excl = s_boff + woff + incl - tsum;
    if (base + 3 < N_NODES) {
        int4 o;
        o.x = excl;
        o.y = excl + v.x;
        o.z = excl + v.x + v.y;
        o.w = excl + v.x + v.y + v.z;
        *(int4*)&offs[base] = o;
        *(int4*)&cursor[base] = o;
    }
}

__global__ void k_fill(const int* __restrict__ src, const int* __restrict__ dst,
                       int* __restrict__ cursor,
                       int* __restrict__ esrc, int n_edges) {
    const int g = blockIdx.x & (FG - 1);
    const int blk = blockIdx.x >> 3;
    const int lo = g * GRANGE, hi = lo + GRANGE;
    const int base = blk * blockDim.x + threadIdx.x;
    const int step = FB * blockDim.x;
    for (int i = base; i * 4 < n_edges; i += step) {
        const int4 d4 = *(const int4*)&dst[i * 4];
        const int4 s4 = *(const int4*)&src[i * 4];
        if (d4.x >= lo && d4.x < hi) esrc[atomicAdd(&cursor[d4.x], 1)] = s4.x;
        if (d4.y >= lo && d4.y < hi) esrc[atomicAdd(&cursor[d4.y], 1)] = s4.y;
        if (d4.z >= lo && d4.z < hi) esrc[atomicAdd(&cursor[d4.z], 1)] = s4.z;
        if (d4.w >= lo && d4.w < hi) esrc[atomicAdd(&cursor[d4.w], 1)] = s4.w;
    }
}

// ---------------------------------------------------------------------------
// s1/d1 via folded attention vectors:  s1[n] = x[n]·(W1 a_src), etc.
// ---------------------------------------------------------------------------
__global__ void k_sd1(const float* __restrict__ x, const float* __restrict__ W1,
                      const float* __restrict__ a1,
                      float* __restrict__ s1, float* __restrict__ d1) {
    __shared__ float bs[IN_DIM], bd[IN_DIM];
    const int t = threadIdx.x;
    if (t < 16) {
        const int k = t & 7;
        const float* av = a1 + ((t < 8) ? 0 : D1);
        float acc = 0.f;
        for (int j = 0; j < D1; ++j) acc += W1[k * D1 + j] * av[j];
        if (t < 8) bs[k] = acc; else bd[k] = acc;
    }
    __syncthreads();
    const int node = blockIdx.x * blockDim.x + t;
    if (node >= N_NODES) return;
    const float4 x0 = *(const float4*)&x[node * 8];
    const float4 x1 = *(const float4*)&x[node * 8 + 4];
    s1[node] = x0.x*bs[0] + x0.y*bs[1] + x0.z*bs[2] + x0.w*bs[3]
             + x1.x*bs[4] + x1.y*bs[5] + x1.z*bs[6] + x1.w*bs[7];
    d1[node] = x0.x*bd[0] + x0.y*bd[1] + x0.z*bd[2] + x0.w*bd[3]
             + x1.x*bd[4] + x1.y*bd[5] + x1.z*bd[6] + x1.w*bd[7];
}

// ---------------------------------------------------------------------------
// Layer-1 aggregation in INPUT space (8-dim), TWO NODES PER WAVE (32 lanes
// per node).  Fast path deg<=32 register-resident; 4 lanes/edge (float2) ->
// 8 edge slots per half.  All shuffles half-local (base = lane&32).
// ---------------------------------------------------------------------------
__global__ void k_aggr_x(const int* __restrict__ esrc, const int* __restrict__ offs,
                         const float* __restrict__ s, const float* __restrict__ d,
                         const float* __restrict__ x, float* __restrict__ xa) {
    const int w = (blockIdx.x * blockDim.x + threadIdx.x) >> 6;
    const int lane = threadIdx.x & 63;
    const int half = lane >> 5, sub = lane & 31, base = lane & 32;
    const int node = w * 2 + half;
    if (node >= N_NODES) return;
    const int start = offs[node], end = offs[node + 1];
    const int deg = end - start;
    const float dn = d[node];
    const int slot = sub >> 2;       // 8 edge slots per half
    const int cp = sub & 3;          // float2 -> cols 2cp, 2cp+1
    float2 acc = {0.f, 0.f};
    float inv;
    if (deg <= 32) {
        int sev = 0; float wv = 0.f;
        if (sub < deg) {
            sev = esrc[start + sub];
            float a = s[sev] + dn;
            a = a > 0.f ? a : 0.2f * a;
            wv = expf(a);
        }
        float sum = wv;
#pragma unroll
        for (int off = 16; off > 0; off >>= 1) sum += __shfl_xor(sum, off);
        inv = 1.f / (sum + 1e-9f);
        for (int i = 0; i < deg; i += 8) {
            const int idx = i + slot;
            const float ww = __shfl(wv, base + idx);
            const int se = __shfl(sev, base + idx);
            if (idx < deg) {
                const float2 v = *(const float2*)&x[se * IN_DIM + cp * 2];
                acc.x += ww * v.x;
                acc.y += ww * v.y;
            }
        }
    } else {
        float sum = 0.f;
        for (int e = start + sub; e < end; e += 32) {
            float a = s[esrc[e]] + dn;
            a = a > 0.f ? a : 0.2f * a;
            sum += expf(a);
        }
#pragma unroll
        for (int off = 16; off > 0; off >>= 1) sum += __shfl_xor(sum, off);
        inv = 1.f / (sum + 1e-9f);
        for (int chunk = start; chunk < end; chunk += 32) {
            const int cnt = min(32, end - chunk);
            int sev = 0; float wv = 0.f;
            if (sub < cnt) {
                sev = esrc[chunk + sub];
                float a = s[sev] + dn;
                a = a > 0.f ? a : 0.2f * a;
                wv = expf(a);
            }
            for (int i = 0; i < cnt; i += 8) {
                const int idx = i + slot;
                const float ww = __shfl(wv, base + idx);
                const int se = __shfl(sev, base + idx);
                if (idx < cnt) {
                    const float2 v = *(const float2*)&x[se * IN_DIM + cp * 2];
                    acc.x += ww * v.x;
                    acc.y += ww * v.y;
                }
            }
        }
    }
    acc.x *= inv;  acc.y *= inv;
    // reduce over slot bits 2..4 (stays within the 32-lane half)
#pragma unroll
    for (int off = 4; off < 32; off <<= 1) {
        acc.x += __shfl_xor(acc.x, off);
        acc.y += __shfl_xor(acc.y, off);
    }
    if (sub < 4) *(float2*)&xa[node * IN_DIM + sub * 2] = acc;
}

// ---------------------------------------------------------------------------
// Fused node mid, 4 THREADS PER NODE (column split).  Thread q of a node
// owns output cols [8q, 8q+8).  h_k recomputed per thread (8 FMA, s_load
// weights, wave-uniform k -> whole wave touches one W2 row per iter).
// ---------------------------------------------------------------------------
__global__ void k_node_mid(const float* __restrict__ xa,
                           const float* __restrict__ W1,
                           const float* __restrict__ W2,
                           const float* __restrict__ a2,
                           float* __restrict__ Wh2,
                           float* __restrict__ s2, float* __restrict__ d2) {
    const int tid = blockIdx.x * blockDim.x + threadIdx.x;
    const int node = tid >> 2;
    const int q = tid & 3;                 // column quarter
    if (node >= N_NODES) return;
    const float4 x0 = *(const float4*)&xa[node * 8];
    const float4 x1 = *(const float4*)&xa[node * 8 + 4];
    float acc[8];
#pragma unroll
    for (int j = 0; j < 8; ++j) acc[j] = 0.f;
    const float* W2q = W2 + q * 8;
#pragma unroll 4
    for (int k = 0; k < D1; ++k) {
        float h = x0.x * W1[0 * D1 + k] + x0.y * W1[1 * D1 + k]
                + x0.z * W1[2 * D1 + k] + x0.w * W1[3 * D1 + k]
                + x1.x * W1[4 * D1 + k] + x1.y * W1[5 * D1 + k]
                + x1.z * W1[6 * D1 + k] + x1.w * W1[7 * D1 + k];
        h = h > 0.f ? h : (expf(h) - 1.f);       // elu
        const float4 w0 = *(const float4*)&W2q[k * HID];
        const float4 w1 = *(const float4*)&W2q[k * HID + 4];
        acc[0] += h * w0.x;  acc[1] += h * w0.y;
        acc[2] += h * w0.z;  acc[3] += h * w0.w;
        acc[4] += h * w1.x;  acc[5] += h * w1.y;
        acc[6] += h * w1.z;  acc[7] += h * w1.w;
    }
    float ss = 0.f, dd = 0.f;
#pragma unroll
    for (int j = 0; j < 8; ++j) {
        ss += acc[j] * a2[q * 8 + j];
        dd += acc[j] * a2[HID + q * 8 + j];
    }
    ss += __shfl_xor(ss, 1);  ss += __shfl_xor(ss, 2);
    dd += __shfl_xor(dd, 1);  dd += __shfl_xor(dd, 2);
    if (q == 0) { s2[node] = ss; d2[node] = dd; }
    float4* o = (float4*)&Wh2[node * HID + q * 8];
    o[0] = make_float4(acc[0], acc[1], acc[2], acc[3]);
    o[1] = make_float4(acc[4], acc[5], acc[6], acc[7]);
}

// ---------------------------------------------------------------------------
// Layer-2 aggregation + FUSED MLP HEAD, TWO NODES PER WAVE (32 lanes/node).
// 16 lanes/edge (float2) -> 2 edge slots per half; head runs concurrently on
// both halves.  All shuffles half-local.
// ---------------------------------------------------------------------------
__global__ void k_aggr32_head(const int* __restrict__ esrc, const int* __restrict__ offs,
                              const float* __restrict__ s, const float* __restrict__ d,
                              const float* __restrict__ Wh,
                              const float* __restrict__ hw1, const float* __restrict__ hb1,
                              const float* __restrict__ hw2, const float* __restrict__ hb2,
                              float* __restrict__ scores) {
    const int w = (blockIdx.x * blockDim.x + threadIdx.x) >> 6;
    const int lane = threadIdx.x & 63;
    const int half = lane >> 5, sub = lane & 31, base = lane & 32;
    const int node = w * 2 + half;
    if (node >= N_NODES) return;
    const int start = offs[node], end = offs[node + 1];
    const int deg = end - start;
    const float dn = d[node];
    const int slot = sub >> 4;       // 2 edge slots per half
    const int cp = sub & 15;         // float2 -> cols 2cp, 2cp+1
    float2 acc = {0.f, 0.f};
    float inv;
    if (deg <= 32) {
        int sev = 0; float wv = 0.f;
        if (sub < deg) {
            sev = esrc[start + sub];
            float a = s[sev] + dn;
            a = a > 0.f ? a : 0.2f * a;
            wv = expf(a);
        }
        float sum = wv;
#pragma unroll
        for (int off = 16; off > 0; off >>= 1) sum += __shfl_xor(sum, off);
        inv = 1.f / (sum + 1e-9f);
        for (int i = 0; i < deg; i += 2) {
            const int idx = i + slot;
            const float ww = __shfl(wv, base + idx);
            const int se = __shfl(sev, base + idx);
            if (idx < deg) {
                const float2 v = *(const float2*)&Wh[se * HID + cp * 2];
                acc.x += ww * v.x;
                acc.y += ww * v.y;
            }
        }
    } else {
        float sum = 0.f;
        for (int e = start + sub; e < end; e += 32) {
            float a = s[esrc[e]] + dn;
            a = a > 0.f ? a : 0.2f * a;
            sum += expf(a);
        }
#pragma unroll
        for (int off = 16; off > 0; off >>= 1) sum += __shfl_xor(sum, off);
        inv = 1.f / (sum + 1e-9f);
        for (int chunk = start; chunk < end; chunk += 32) {
            const int cnt = min(32, end - chunk);
            int sev = 0; float wv = 0.f;
            if (sub < cnt) {
                sev = esrc[chunk + sub];
                float a = s[sev] + dn;
                a = a > 0.f ? a : 0.2f * a;
                wv = expf(a);
            }
            for (int i = 0; i < cnt; i += 2) {
                const int idx = i + slot;
                const float ww = __shfl(wv, base + idx);
                const int se = __shfl(sev, base + idx);
                if (idx < cnt) {
                    const float2 v = *(const float2*)&Wh[se * HID + cp * 2];
                    acc.x += ww * v.x;
                    acc.y += ww * v.y;
                }
            }
        }
    }
    acc.x *= inv;  acc.y *= inv;
    acc.x += __shfl_xor(acc.x, 16);      // combine the 2 slots (within half)
    acc.y += __shfl_xor(acc.y, 16);
    // ---- fused head (per half; lane sub = output col c) ----
    const float hx = __shfl(acc.x, base + (sub >> 1));
    const float hy = __shfl(acc.y, base + (sub >> 1));
    float v = (sub & 1) ? hy : hx;
    const float h = v > 0.f ? v : (expf(v) - 1.f);   // elu
    float z = hb1[sub];
#pragma unroll
    for (int k = 0; k < HID; ++k) {
        const float hk = __shfl(h, base + k);        // h_k lives in lane base+k
        z += hk * hw1[k * HID + sub];
    }
    z = 0.5f * z * (1.f + erff(z * 0.7071067811865475f));  // exact gelu
    float sc = z * hw2[sub];
#pragma unroll
    for (int off = 16; off > 0; off >>= 1) sc += __shfl_xor(sc, off);
    if (sub == 0) scores[node] = sc + hb2[0];
}

// ---------------------------------------------------------------------------
extern "C" void kernel_launch(void* const* d_in, const int* in_sizes, int n_in,
                              void* d_out, int out_size, void* d_ws, size_t ws_size,
                              hipStream_t stream) {
    const float* x   = (const float*)d_in[0];
    const int*   ei  = (const int*)d_in[1];
    const float* W1  = (const float*)d_in[2];
    const float* a1  = (const float*)d_in[3];
    const float* W2  = (const float*)d_in[4];
    const float* a2  = (const float*)d_in[5];
    const float* hw1 = (const float*)d_in[6];
    const float* hb1 = (const float*)d_in[7];
    const float* hw2 = (const float*)d_in[8];
    const float* hb2 = (const float*)d_in[9];
    float* out = (float*)d_out;

    const int n_edges = in_sizes[1] / 2;
    const int* src = ei;
    const int* dst = ei + n_edges;

    // workspace carve-up
    float* p = (float*)d_ws;
    float* xa   = p; p += (size_t)N_NODES * IN_DIM;
    float* Wh2  = p; p += (size_t)N_NODES * HID;
    float* s1   = p; p += N_NODES;
    float* d1   = p; p += N_NODES;
    float* s2   = p; p += N_NODES;
    float* d2   = p; p += N_NODES;
    int* cnt    = (int*)p; p += N_NODES;        // histogram counts
    int* cursor = (int*)p; p += N_NODES;        // fill cursors (init by scan_c)
    int* offs   = (int*)p; p += N_NODES + 1;    // CSR offsets
    int* esrc   = (int*)p; p += n_edges;        // src ids sorted by dst
    int* bsum   = (int*)p; p += NB;             // scan block sums

    hipMemsetAsync(cnt, 0, N_NODES * sizeof(int), stream);

    const int AGGR_BLOCKS = (N_NODES * 32 + 255) / 256;   // 2 nodes per wave

    // CSR build (XCD-partitioned atomics/scatter)
    k_hist<<<FG * FB, 256, 0, stream>>>(dst, cnt, n_edges);
    k_scan_a<<<NB, 256, 0, stream>>>(cnt, bsum);
    k_scan_c<<<NB, 256, 0, stream>>>(cnt, bsum, offs, cursor);
    k_fill<<<FG * FB, 256, 0, stream>>>(src, dst, cursor, esrc, n_edges);

    // ----- layer 1 (aggregated in 8-dim input space; Wh1 never built) -----
    k_sd1<<<(N_NODES + 255) / 256, 256, 0, stream>>>(x, W1, a1, s1, d1);
    k_aggr_x<<<AGGR_BLOCKS, 256, 0, stream>>>(esrc, offs, s1, d1, x, xa);

    // ----- layer 2 (4-thread-per-node mid; aggregation fused with head) -----
    k_node_mid<<<(N_NODES * 4 + 255) / 256, 256, 0, stream>>>(xa, W1, W2, a2, Wh2, s2, d2);
    k_aggr32_head<<<AGGR_BLOCKS, 256, 0, stream>>>(esrc, offs, s2, d2, Wh2,
                                                   hw1, hb1, hw2, hb2, out);
}